// Round 7
// baseline (173.672 us; speedup 1.0000x reference)
//
#include <hip/hip_runtime.h>
#include <cfloat>
#include <cstdint>

#define BATCH 16
#define PRIORS 3000
#define NCLS 201
#define NLBL 200           // NCLS - 1
#define TOPN 100
#define SCORE_THR 0.02f
#define NMS_THR 0.45f

// filter v3: 256-thread blocks, 4 waves, 4 priors per wave (serial depth 4).
// Each wave owns a fixed 64-slot segment of global key space -> ballot
// compaction, NO atomics, NO LDS, NO barriers. Mean 23.5 cand/wave,
// sigma 4.8 -> 64 slots = +8.4 sigma; overflow -> atomic region (exact).
#define FPPB 16                              // priors per block
#define FBLK ((PRIORS + FPPB - 1) / FPPB)    // 188 blocks/image
#define SEGW 64                              // slots per wave-segment
#define SEGS (FBLK * 4)                      // 752 segments/image
#define SLOTS (SEGS * SEGW)                  // 48128 slots/image
#define OVF_CAP 1024

// nms: sorted-scan (greedy NMS == descending-key scan, accept iff not
// suppressed by an earlier accept; keys distinct -> total order ==
// jnp.argmax semantics). key = (float_bits(prob)<<32) | (0xFFFFFFFF-oid).
#define NMS_T 1024
#define NBINS 1024         // strata over (key>>48)-SB_BASE, natural range 0..733
#define CHUNK 1024
#define SB_BASE 0x3CA3     // floatbits(0.02) >> 16

__device__ __forceinline__ int key_stratum(uint64_t k) {
    int s = (int)(k >> 48) - SB_BASE;
    return s < 0 ? 0 : (s > NBINS - 1 ? NBINS - 1 : s);
}

// ---------------------------------------------------------------------------
// Kernel B (v3): softmax + filter, wave-segmented output.
// Softmax arithmetic identical to R2-R6 (bit-stable, absmax 0.0).
// ---------------------------------------------------------------------------
__global__ __launch_bounds__(256) void score_filter_kernel(
    const float* __restrict__ obj,      // [B][P][NCLS]
    int*         __restrict__ cnt,      // [B] overflow counters (memset 0)
    uint64_t*    __restrict__ seg,      // [B][SEGS][SEGW]
    uint64_t*    __restrict__ ovf)      // [B][OVF_CAP]
{
    const int b    = blockIdx.y;
    const int wave = threadIdx.x >> 6;
    const int lane = threadIdx.x & 63;
    const int segId = blockIdx.x * 4 + wave;
    uint64_t* myseg = seg + ((size_t)b * SEGS + segId) * SEGW;

    int cursor = 0;
#pragma unroll
    for (int pp = 0; pp < 4; ++pp) {
        int p = blockIdx.x * FPPB + wave * 4 + pp;
        if (p < PRIORS) {                         // wave-uniform guard
            const float* x = obj + ((size_t)b * PRIORS + p) * NCLS;
            float v0 = x[lane];
            float v1 = x[lane + 64];
            float v2 = x[lane + 128];
            float v3 = (lane + 192 < NCLS) ? x[lane + 192] : -FLT_MAX;
            float mx = fmaxf(fmaxf(v0, v1), fmaxf(v2, v3));
            for (int d = 32; d > 0; d >>= 1) mx = fmaxf(mx, __shfl_xor(mx, d, 64));
            float e0 = expf(v0 - mx), e1 = expf(v1 - mx), e2 = expf(v2 - mx);
            float e3 = (lane + 192 < NCLS) ? expf(v3 - mx) : 0.0f;
            float se = e0 + e1 + e2 + e3;
            for (int d = 32; d > 0; d >>= 1) se += __shfl_xor(se, d, 64);
            float inv = 1.0f / se;
            float ev[4] = { e0, e1, e2, e3 };
#pragma unroll
            for (int k = 0; k < 4; ++k) {
                int c = lane + 64 * k;
                float prob = ev[k] * inv;
                bool pass = (c >= 1) && (c < NCLS) && (prob > SCORE_THR);
                uint64_t mask = __ballot(pass);
                if (pass) {
                    uint32_t oid = (uint32_t)(p * NLBL + (c - 1));
                    uint64_t key = ((uint64_t)__float_as_uint(prob) << 32)
                                 | (uint64_t)(0xFFFFFFFFu - oid);
                    int idx = cursor + __popcll(mask & ((1ull << lane) - 1ull));
                    if (idx < SEGW) {
                        myseg[idx] = key;
                    } else {                      // exact overflow path (never taken)
                        int gi = atomicAdd(&cnt[b], 1);
                        if (gi < OVF_CAP) ovf[(size_t)b * OVF_CAP + gi] = key;
                    }
                }
                cursor += (int)__popcll(mask);
            }
        }
    }
    // zero-fill segment tail (nms skips key==0)
    int cc = cursor < SEGW ? cursor : SEGW;
    if (lane >= cc) myseg[lane] = 0ull;           // SEGW == 64
}

// ---------------------------------------------------------------------------
// Wave-0 scan step, all-LDS. Box/area reconstructed bit-identically to the
// reference's bo/areas: offset box = dec[p] + c*off; area from offset
// coords. IoU operand order matches reference.
// ---------------------------------------------------------------------------
__device__ __forceinline__ int scan_step_w0(
    uint64_t key, int b, const float4* __restrict__ dbox, float ofb,
    float4* abox, float* aarea, int na, float* __restrict__ out, int lane)
{
    uint32_t oid = 0xFFFFFFFFu - (uint32_t)key;
    int p = (int)(oid / NLBL);
    int c = (int)(oid - (uint32_t)p * NLBL) + 1;
    float4 db = dbox[p];                            // LDS broadcast
    float lo = (float)c * ofb;
    float qx1 = db.x + lo, qy1 = db.y + lo;
    float qx2 = db.z + lo, qy2 = db.w + lo;
    float aq = (qx2 - qx1) * (qy2 - qy1);
    bool sup = false;
    for (int l = lane; l < na; l += 64) {
        float4 a = abox[l];
        float ix1 = fmaxf(qx1, a.x);
        float iy1 = fmaxf(qy1, a.y);
        float ix2 = fminf(qx2, a.z);
        float iy2 = fminf(qy2, a.w);
        float inter = fmaxf(ix2 - ix1, 0.0f) * fmaxf(iy2 - iy1, 0.0f);
        float iou = inter / (aq + aarea[l] - inter);   // NaN>thr==false, like jnp
        if (iou > NMS_THR) sup = true;
    }
    if (__ballot(sup) == 0ull) {
        if (lane == 0) {
            abox[na]  = make_float4(qx1, qy1, qx2, qy2);
            aarea[na] = aq;
            float* o = out + ((size_t)b * TOPN + na) * 6;
            o[0] = fminf(fmaxf(db.x, 0.0f), 1.0f);
            o[1] = fminf(fmaxf(db.y, 0.0f), 1.0f);
            o[2] = fminf(fmaxf(db.z, 0.0f), 1.0f);
            o[3] = fminf(fmaxf(db.w, 0.0f), 1.0f);
            o[4] = __uint_as_float((uint32_t)(key >> 32));
            o[5] = (float)c;
        }
        __threadfence_block();
        return na + 1;
    }
    return na;
}

// ---------------------------------------------------------------------------
// Kernel C (v7): one block per image, decode fused (LDS dbox).
// Changes vs v6: (1) wave-parallel suffix scan (3 barriers, was 20);
// (2) hybrid register/LDS bitonic: j2<=32 stages via shfl_xor (45 stages,
// barrier-free), j2>=64 via LDS (10 stages, 20 barriers) -- was 55
// barriered LDS stages; (3) consumes wave-segments + overflow (key==0
// slots skipped; order-independent multiset semantics).
// ---------------------------------------------------------------------------
__global__ __launch_bounds__(NMS_T) void nms_kernel(
    const float*    __restrict__ deltas,  // [B][P][4]
    const float*    __restrict__ priors,  // [P][4]
    const int*      __restrict__ cnt,     // [B] overflow counts
    const uint64_t* __restrict__ seg,     // [B][SLOTS]
    const uint64_t* __restrict__ ovf,     // [B][OVF_CAP]
    float*          __restrict__ out)     // [B][TOPN][6]
{
    __shared__ float4   dbox[PRIORS];     // 48 KB decoded boxes
    __shared__ int      sufx[NBINS];      // hist -> inclusive suffix counts
    __shared__ uint64_t skey[CHUNK];
    __shared__ float4   abox[112];
    __shared__ float    aarea[112];
    __shared__ uint64_t rk[NMS_T / 64];
    __shared__ float    wredF[NMS_T / 64];
    __shared__ int      wtotS[NMS_T / 64];
    __shared__ int      carryS[NMS_T / 64];
    __shared__ int lcolS, loS, naS;
    __shared__ uint64_t fkS;
    __shared__ float ofbS;

    const int b    = blockIdx.x;
    const int tid  = threadIdx.x;
    const int wave = tid >> 6;
    const int lane = tid & 63;
    const uint64_t* slots = seg + (size_t)b * SLOTS;
    int n_ovf = cnt[b]; if (n_ovf > OVF_CAP) n_ovf = OVF_CAP;
    const uint64_t* ovfp = ovf + (size_t)b * OVF_CAP;

    // ---- Phase 0: decode into LDS + max reduce (exprs identical R1-R6) ----
    float lmax = -FLT_MAX;
    for (int p = tid; p < PRIORS; p += NMS_T) {
        float4 d4 = ((const float4*)deltas)[(size_t)b * PRIORS + p];
        float4 pr = ((const float4*)priors)[p];
        float cx = d4.x * 0.1f * pr.z + pr.x;
        float cy = d4.y * 0.1f * pr.w + pr.y;
        float w  = expf(d4.z * 0.2f) * pr.z;
        float h  = expf(d4.w * 0.2f) * pr.w;
        float x1 = cx - 0.5f * w, y1 = cy - 0.5f * h;
        float x2 = cx + 0.5f * w, y2 = cy + 0.5f * h;
        dbox[p] = make_float4(x1, y1, x2, y2);
        lmax = fmaxf(lmax, fmaxf(fmaxf(x1, y1), fmaxf(x2, y2)));
    }
    for (int d = 32; d > 0; d >>= 1)
        lmax = fmaxf(lmax, __shfl_xor(lmax, d, 64));
    if (lane == 0) wredF[wave] = lmax;
    sufx[tid] = 0;                          // NBINS == NMS_T
    if (tid == 0) naS = 0;
    __syncthreads();
    if (tid == 0) {
        float m = wredF[0];
        for (int w = 1; w < NMS_T / 64; ++w) m = fmaxf(m, wredF[w]);
        ofbS = m + 1.0f;
    }
    // ---- histogram over score strata (skip zero slots) ----
#pragma unroll 4
    for (int j = tid; j < SLOTS; j += NMS_T) {
        uint64_t k = slots[j];
        if (k) atomicAdd(&sufx[key_stratum(k)], 1);
    }
    for (int j = tid; j < n_ovf; j += NMS_T) {
        uint64_t k = ovfp[j];
        if (k) atomicAdd(&sufx[key_stratum(k)], 1);
    }
    __syncthreads();
    // ---- wave-parallel inclusive suffix sum over 1024 bins ----
    {
        int v = sufx[64 * wave + lane];
        int s = v;
        for (int d = 1; d < 64; d <<= 1) {
            int t = __shfl_down(s, d, 64);
            if (lane + d < 64) s += t;
        }
        if (lane == 0) wtotS[wave] = s;     // wave-chunk total
        __syncthreads();
        if (wave == 0 && lane < NMS_T / 64) {
            int tv = wtotS[lane];
            int ts = tv;
            for (int d = 1; d < NMS_T / 64; d <<= 1) {
                int t = __shfl_down(ts, d, 64);
                if (lane + d < NMS_T / 64) ts += t;
            }
            carryS[lane] = ts - tv;         // exclusive suffix of totals
        }
        __syncthreads();
        sufx[64 * wave + lane] = s + carryS[wave];
    }
    __syncthreads();
    const float ofb = ofbS;

    int curHi = NBINS;
    for (;;) {
        __syncthreads();
        int naCur = naS;
        int A = (curHi < NBINS) ? sufx[curHi] : 0;
        int remaining = sufx[0] - A;
        if (naCur >= TOPN || remaining <= 0 || curHi <= 0) break;
        int target = A + CHUNK;
        if (tid == 0) loS = curHi;
        __syncthreads();
        if (tid < curHi) {
            if (sufx[tid] <= target && (tid == 0 || sufx[tid - 1] > target))
                loS = tid;
        }
        __syncthreads();
        int lo = loS;

        if (lo < curHi) {
            // ---------------- chunk path (common) ----------------
            if (tid == 0) lcolS = 0;
            __syncthreads();
#pragma unroll 4
            for (int j = tid; j < SLOTS; j += NMS_T) {
                uint64_t k = slots[j];
                if (k) {
                    int s = key_stratum(k);
                    if (s >= lo && s < curHi) skey[atomicAdd(&lcolS, 1)] = k;
                }
            }
            for (int j = tid; j < n_ovf; j += NMS_T) {
                uint64_t k = ovfp[j];
                if (k) {
                    int s = key_stratum(k);
                    if (s >= lo && s < curHi) skey[atomicAdd(&lcolS, 1)] = k;
                }
            }
            __syncthreads();
            int lcol = lcolS;
            if (tid >= lcol) skey[tid] = 0ull;      // CHUNK == NMS_T
            __syncthreads();
            // ---- hybrid bitonic sort, descending by full u64 key ----
            uint64_t k = skey[tid];
            for (int k2 = 2; k2 <= CHUNK; k2 <<= 1) {
                const bool up = ((tid & k2) == 0);
                for (int j2 = k2 >> 1; j2 >= 64; j2 >>= 1) {   // LDS stages
                    __syncthreads();
                    skey[tid] = k;
                    __syncthreads();
                    uint64_t o = skey[tid ^ j2];
                    bool lower = ((tid & j2) == 0);
                    bool takeMax = (up == lower);
                    k = takeMax ? (k > o ? k : o) : (k < o ? k : o);
                }
                int j2s = (k2 >> 1) < 32 ? (k2 >> 1) : 32;
                for (int j2 = j2s; j2 >= 1; j2 >>= 1) {        // shuffle stages
                    uint64_t o = __shfl_xor((unsigned long long)k, j2, 64);
                    bool lower = ((tid & j2) == 0);
                    bool takeMax = (up == lower);
                    k = takeMax ? (k > o ? k : o) : (k < o ? k : o);
                }
            }
            __syncthreads();
            skey[tid] = k;
            __syncthreads();
            // ---- sorted scan on wave 0 (all-LDS) ----
            if (wave == 0) {
                int nal = naS;
                for (int i = 0; i < lcol && nal < TOPN; ++i)
                    nal = scan_step_w0(skey[i], b, dbox, ofb, abox, aarea, nal, out, lane);
                if (lane == 0) naS = nal;
            }
            curHi = lo;
        } else {
            // ------- overfull stratum (>1024 same score-prefix; never with
            //         this data): exact extraction by repeated block argmax -------
            int s = curHi - 1;
            uint64_t lastK = ~0ull;
            for (;;) {
                __syncthreads();
                if (naS >= TOPN) break;
                uint64_t bk = 0ull;
                for (int j = tid; j < SLOTS; j += NMS_T) {
                    uint64_t k = slots[j];
                    if (k && key_stratum(k) == s && k < lastK && k > bk) bk = k;
                }
                for (int j = tid; j < n_ovf; j += NMS_T) {
                    uint64_t k = ovfp[j];
                    if (k && key_stratum(k) == s && k < lastK && k > bk) bk = k;
                }
                for (int d = 32; d > 0; d >>= 1) {
                    uint64_t o = __shfl_xor((unsigned long long)bk, d, 64);
                    bk = (o > bk) ? o : bk;
                }
                if (lane == 0) rk[wave] = bk;
                __syncthreads();
                if (tid == 0) {
                    uint64_t fk = rk[0];
                    for (int w = 1; w < NMS_T / 64; ++w) fk = (rk[w] > fk) ? rk[w] : fk;
                    fkS = fk;
                }
                __syncthreads();
                uint64_t fk = fkS;
                if (fk == 0ull) break;
                if (wave == 0) {
                    int nal = naS;
                    nal = scan_step_w0(fk, b, dbox, ofb, abox, aarea, nal, out, lane);
                    if (lane == 0) naS = nal;
                }
                lastK = fk;
            }
            curHi = s;
        }
    }
    // ---- zero-fill rows naS..99 (harness poisons d_out) ----
    __syncthreads();
    int naF = naS;
    for (int idx = tid; idx < (TOPN - naF) * 6; idx += NMS_T)
        out[(size_t)b * TOPN * 6 + (size_t)naF * 6 + idx] = 0.0f;
}

// ---------------------------------------------------------------------------
extern "C" void kernel_launch(void* const* d_in, const int* in_sizes, int n_in,
                              void* d_out, int out_size, void* d_ws, size_t ws_size,
                              hipStream_t stream)
{
    const float* deltas = (const float*)d_in[0];
    const float* obj    = (const float*)d_in[1];
    const float* priors = (const float*)d_in[2];
    float* out = (float*)d_out;

    char* ws = (char*)d_ws;
    int* cnt = (int*)ws;                                    // B ints (overflow)
    uint64_t* seg = (uint64_t*)(ws + 256);                  // B*SLOTS keys (6.2 MB)
    uint64_t* ovf = seg + (size_t)BATCH * SLOTS;            // B*OVF_CAP keys (128 KB)

    hipMemsetAsync(cnt, 0, BATCH * sizeof(int), stream);
    dim3 fg(FBLK, BATCH, 1);
    score_filter_kernel<<<fg, 256, 0, stream>>>(obj, cnt, seg, ovf);
    nms_kernel<<<BATCH, NMS_T, 0, stream>>>(deltas, priors, cnt, seg, ovf, out);
}

// Round 8
// 159.253 us; speedup vs baseline: 1.0905x; 1.0905x over previous
//
#include <hip/hip_runtime.h>
#include <cfloat>
#include <cstdint>

#define BATCH 16
#define PRIORS 3000
#define NCLS 201
#define NLBL 200           // NCLS - 1
#define TOPN 100
#define SCORE_THR 0.02f
#define NMS_THR 0.45f

// filter v3 (unchanged from R7): 256-thread blocks, 4 waves, 4 priors/wave.
// Wave-segmented ballot compaction, no atomics/LDS/barriers.
#define FPPB 16                              // priors per block
#define FBLK ((PRIORS + FPPB - 1) / FPPB)    // 188 blocks/image
#define SEGW 64                              // slots per wave-segment
#define SEGS (FBLK * 4)                      // 752 segments/image
#define SLOTS (SEGS * SEGW)                  // 48128 slots/image
#define OVF_CAP 1024

// nms v8: sorted-scan with wave-register sort (256 keys in one wave's regs)
// and wave-batched scan. key = (float_bits(prob)<<32) | (0xFFFFFFFF-oid).
#define NMS_T 1024
#define NBINS 1024         // strata over (key>>48)-SB_BASE, natural range 0..733
#define CHUNK 256          // 100th accept sits at sorted rank ~105
#define SB_BASE 0x3CA3     // floatbits(0.02) >> 16

__device__ __forceinline__ int key_stratum(uint64_t k) {
    int s = (int)(k >> 48) - SB_BASE;
    return s < 0 ? 0 : (s > NBINS - 1 ? NBINS - 1 : s);
}

// ---------------------------------------------------------------------------
// Kernel B: softmax + filter, wave-segmented output (identical to R7).
// Softmax arithmetic identical to R2-R7 (bit-stable, absmax 0.0).
// ---------------------------------------------------------------------------
__global__ __launch_bounds__(256) void score_filter_kernel(
    const float* __restrict__ obj,      // [B][P][NCLS]
    int*         __restrict__ cnt,      // [B] overflow counters (memset 0)
    uint64_t*    __restrict__ seg,      // [B][SEGS][SEGW]
    uint64_t*    __restrict__ ovf)      // [B][OVF_CAP]
{
    const int b    = blockIdx.y;
    const int wave = threadIdx.x >> 6;
    const int lane = threadIdx.x & 63;
    const int segId = blockIdx.x * 4 + wave;
    uint64_t* myseg = seg + ((size_t)b * SEGS + segId) * SEGW;

    int cursor = 0;
#pragma unroll
    for (int pp = 0; pp < 4; ++pp) {
        int p = blockIdx.x * FPPB + wave * 4 + pp;
        if (p < PRIORS) {                         // wave-uniform guard
            const float* x = obj + ((size_t)b * PRIORS + p) * NCLS;
            float v0 = x[lane];
            float v1 = x[lane + 64];
            float v2 = x[lane + 128];
            float v3 = (lane + 192 < NCLS) ? x[lane + 192] : -FLT_MAX;
            float mx = fmaxf(fmaxf(v0, v1), fmaxf(v2, v3));
            for (int d = 32; d > 0; d >>= 1) mx = fmaxf(mx, __shfl_xor(mx, d, 64));
            float e0 = expf(v0 - mx), e1 = expf(v1 - mx), e2 = expf(v2 - mx);
            float e3 = (lane + 192 < NCLS) ? expf(v3 - mx) : 0.0f;
            float se = e0 + e1 + e2 + e3;
            for (int d = 32; d > 0; d >>= 1) se += __shfl_xor(se, d, 64);
            float inv = 1.0f / se;
            float ev[4] = { e0, e1, e2, e3 };
#pragma unroll
            for (int k = 0; k < 4; ++k) {
                int c = lane + 64 * k;
                float prob = ev[k] * inv;
                bool pass = (c >= 1) && (c < NCLS) && (prob > SCORE_THR);
                uint64_t mask = __ballot(pass);
                if (pass) {
                    uint32_t oid = (uint32_t)(p * NLBL + (c - 1));
                    uint64_t key = ((uint64_t)__float_as_uint(prob) << 32)
                                 | (uint64_t)(0xFFFFFFFFu - oid);
                    int idx = cursor + __popcll(mask & ((1ull << lane) - 1ull));
                    if (idx < SEGW) {
                        myseg[idx] = key;
                    } else {                      // exact overflow path (never taken)
                        int gi = atomicAdd(&cnt[b], 1);
                        if (gi < OVF_CAP) ovf[(size_t)b * OVF_CAP + gi] = key;
                    }
                }
                cursor += (int)__popcll(mask);
            }
        }
    }
    int cc = cursor < SEGW ? cursor : SEGW;
    if (lane >= cc) myseg[lane] = 0ull;           // zero tail; nms skips key==0
}

// ---------------------------------------------------------------------------
// Fallback single-candidate scan step on wave 0 (overfull-stratum path only;
// never taken with this data). Bit-identical box/area/IoU expressions.
// ---------------------------------------------------------------------------
__device__ __forceinline__ int scan_step_w0(
    uint64_t key, int b, const float4* __restrict__ dbox, float ofb,
    float4* abox, float* aarea, int na, float* __restrict__ out, int lane)
{
    uint32_t oid = 0xFFFFFFFFu - (uint32_t)key;
    int p = (int)(oid / NLBL);
    int c = (int)(oid - (uint32_t)p * NLBL) + 1;
    float4 db = dbox[p];
    float lo = (float)c * ofb;
    float qx1 = db.x + lo, qy1 = db.y + lo;
    float qx2 = db.z + lo, qy2 = db.w + lo;
    float aq = (qx2 - qx1) * (qy2 - qy1);
    bool sup = false;
    for (int l = lane; l < na; l += 64) {
        float4 a = abox[l];
        float ix1 = fmaxf(qx1, a.x);
        float iy1 = fmaxf(qy1, a.y);
        float ix2 = fminf(qx2, a.z);
        float iy2 = fminf(qy2, a.w);
        float inter = fmaxf(ix2 - ix1, 0.0f) * fmaxf(iy2 - iy1, 0.0f);
        float iou = inter / (aq + aarea[l] - inter);   // NaN>thr==false, like jnp
        if (iou > NMS_THR) sup = true;
    }
    if (__ballot(sup) == 0ull) {
        if (lane == 0) {
            abox[na]  = make_float4(qx1, qy1, qx2, qy2);
            aarea[na] = aq;
            float* o = out + ((size_t)b * TOPN + na) * 6;
            o[0] = fminf(fmaxf(db.x, 0.0f), 1.0f);
            o[1] = fminf(fmaxf(db.y, 0.0f), 1.0f);
            o[2] = fminf(fmaxf(db.z, 0.0f), 1.0f);
            o[3] = fminf(fmaxf(db.w, 0.0f), 1.0f);
            o[4] = __uint_as_float((uint32_t)(key >> 32));
            o[5] = (float)c;
        }
        __threadfence_block();
        return na + 1;
    }
    return na;
}

// ---------------------------------------------------------------------------
// Kernel C (v8): one block per image.
//  A: histogram over slots -> wave-parallel suffix counts.
//  B: chunk loop (CHUNK=256): collect [lo,curHi) keys into LDS;
//     wave 0 sorts the 256 keys ENTIRELY IN REGISTERS (4/lane; shfl_xor for
//     j2<=32, in-lane reg exchange for j2 in {64,128}) WHILE waves 1-15
//     decode the 3000 priors into LDS dbox (task parallelism, both
//     barrier-free internally); then wave 0 runs a WAVE-BATCHED scan:
//     phase A tests 64 candidates vs accepted list in parallel, phase B
//     resolves within-wave accepts via shuffles (~40 cyc/accept).
//  Greedy-order exactness: sorted full-key desc == jnp.argmax order;
//  accepted lane force-removed (matches .at[i].set(-1), robust to NaN IoU).
// ---------------------------------------------------------------------------
__global__ __launch_bounds__(NMS_T) void nms_kernel(
    const float*    __restrict__ deltas,  // [B][P][4]
    const float*    __restrict__ priors,  // [P][4]
    const int*      __restrict__ cnt,     // [B] overflow counts
    const uint64_t* __restrict__ seg,     // [B][SLOTS]
    const uint64_t* __restrict__ ovf,     // [B][OVF_CAP]
    float*          __restrict__ out)     // [B][TOPN][6]
{
    __shared__ float4   dbox[PRIORS];     // 48 KB decoded boxes
    __shared__ int      sufx[NBINS];      // hist -> inclusive suffix counts
    __shared__ uint64_t skey[CHUNK];      // collected chunk (<=256)
    __shared__ float4   abox[112];        // accepted offset boxes (<=100)
    __shared__ float    aarea[112];
    __shared__ uint64_t rk[NMS_T / 64];
    __shared__ float    wredF[NMS_T / 64];
    __shared__ int      wtotS[NMS_T / 64];
    __shared__ int      carryS[NMS_T / 64];
    __shared__ int cnt256S, loS, naS;
    __shared__ uint64_t fkS;

    const int b    = blockIdx.x;
    const int tid  = threadIdx.x;
    const int wave = tid >> 6;
    const int lane = tid & 63;
    const uint64_t* slots = seg + (size_t)b * SLOTS;
    int n_ovf = cnt[b]; if (n_ovf > OVF_CAP) n_ovf = OVF_CAP;
    const uint64_t* ovfp = ovf + (size_t)b * OVF_CAP;

    // ---- init ----
    sufx[tid] = 0;                          // NBINS == NMS_T
    if (tid == 0) naS = 0;
    if (lane == 0) wredF[wave] = -FLT_MAX;  // wave 0 never decodes
    __syncthreads();

    // ---- Phase A: histogram over score strata (skip zero slots) ----
#pragma unroll 4
    for (int j = tid; j < SLOTS; j += NMS_T) {
        uint64_t k = slots[j];
        if (k) atomicAdd(&sufx[key_stratum(k)], 1);
    }
    for (int j = tid; j < n_ovf; j += NMS_T) {
        uint64_t k = ovfp[j];
        if (k) atomicAdd(&sufx[key_stratum(k)], 1);
    }
    __syncthreads();
    // ---- wave-parallel inclusive suffix sum over 1024 bins ----
    {
        int v = sufx[64 * wave + lane];
        int s = v;
        for (int d = 1; d < 64; d <<= 1) {
            int t = __shfl_down(s, d, 64);
            if (lane + d < 64) s += t;
        }
        if (lane == 0) wtotS[wave] = s;
        __syncthreads();
        if (wave == 0 && lane < NMS_T / 64) {
            int tv = wtotS[lane];
            int ts = tv;
            for (int d = 1; d < NMS_T / 64; d <<= 1) {
                int t = __shfl_down(ts, d, 64);
                if (lane + d < NMS_T / 64) ts += t;
            }
            carryS[lane] = ts - tv;
        }
        __syncthreads();
        sufx[64 * wave + lane] = s + carryS[wave];
    }

    // ---- Phase B: chunk loop ----
    int curHi = NBINS;
    bool decoded = false;
    for (;;) {
        __syncthreads();
        int naCur = naS;
        int A = (curHi < NBINS) ? sufx[curHi] : 0;
        int remaining = sufx[0] - A;
        if (naCur >= TOPN || remaining <= 0 || curHi <= 0) break;
        int target = A + CHUNK;
        if (tid == 0) { loS = curHi; cnt256S = 0; }
        __syncthreads();
        if (tid < curHi) {
            if (sufx[tid] <= target && (tid == 0 || sufx[tid - 1] > target))
                loS = tid;
        }
        __syncthreads();
        int lo = loS;

        if (lo < curHi) {
            // ---- collect [lo, curHi) -> skey (count <= 256 by construction) ----
#pragma unroll 4
            for (int j = tid; j < SLOTS; j += NMS_T) {
                uint64_t k = slots[j];
                if (k) {
                    int s = key_stratum(k);
                    if (s >= lo && s < curHi) skey[atomicAdd(&cnt256S, 1)] = k;
                }
            }
            for (int j = tid; j < n_ovf; j += NMS_T) {
                uint64_t k = ovfp[j];
                if (k) {
                    int s = key_stratum(k);
                    if (s >= lo && s < curHi) skey[atomicAdd(&cnt256S, 1)] = k;
                }
            }
            __syncthreads();
            if (tid >= cnt256S && tid < CHUNK) skey[tid] = 0ull;
            __syncthreads();

            if (wave == 0) {
                // ======== wave 0: register bitonic sort of 256 keys ========
                uint64_t K[4];
#pragma unroll
                for (int r = 0; r < 4; ++r) K[r] = skey[r * 64 + lane];
#pragma unroll
                for (int k2 = 2; k2 <= 256; k2 <<= 1) {
                    // register stages (element distance >= 64)
#pragma unroll
                    for (int j2 = k2 >> 1; j2 >= 64; j2 >>= 1) {
                        int j2r = j2 >> 6;
#pragma unroll
                        for (int r = 0; r < 4; ++r) {
                            if ((r & j2r) == 0) {
                                int rp = r | j2r;
                                bool up = ((((r << 6) + lane) & k2) == 0);
                                uint64_t a = K[r], bb = K[rp];
                                uint64_t mx = a > bb ? a : bb;
                                uint64_t mn = a > bb ? bb : a;
                                K[r]  = up ? mx : mn;
                                K[rp] = up ? mn : mx;
                            }
                        }
                    }
                    // shuffle stages (distance <= 32)
#pragma unroll
                    for (int j2 = ((k2 >> 1) < 32 ? (k2 >> 1) : 32); j2 >= 1; j2 >>= 1) {
#pragma unroll
                        for (int r = 0; r < 4; ++r) {
                            uint64_t o = __shfl_xor((unsigned long long)K[r], j2, 64);
                            bool up = ((((r << 6) + lane) & k2) == 0);
                            bool lower = ((lane & j2) == 0);
                            K[r] = (up == lower) ? (K[r] > o ? K[r] : o)
                                                 : (K[r] < o ? K[r] : o);
                        }
                    }
                }
                // stash sorted keys so the barrier below can separate decode
                // (consumed immediately after; keeps K live in regs anyway)
                __syncthreads();   // decode done on waves 1-15
                // ======== wave-batched sorted scan ========
                float ofb;
                {
                    float v = (lane < NMS_T / 64) ? wredF[lane] : -FLT_MAX;
                    for (int d = 32; d > 0; d >>= 1) v = fmaxf(v, __shfl_xor(v, d, 64));
                    ofb = v + 1.0f;
                }
                int na = naS;
#pragma unroll
                for (int r = 0; r < 4; ++r) {
                    if (na >= TOPN) break;
                    uint64_t myk = K[r];
                    bool valid = (myk != 0ull);
                    uint32_t oid = 0xFFFFFFFFu - (uint32_t)myk;
                    int p = valid ? (int)(oid / NLBL) : 0;
                    int c = valid ? ((int)(oid - (uint32_t)p * NLBL) + 1) : 1;
                    float4 db = dbox[p];
                    float lof = (float)c * ofb;
                    float qx1 = db.x + lof, qy1 = db.y + lof;
                    float qx2 = db.z + lof, qy2 = db.w + lof;
                    float aq = (qx2 - qx1) * (qy2 - qy1);
                    // phase A: parallel test vs existing accepted boxes
                    bool dead = false;
                    for (int l = 0; l < na; ++l) {
                        float4 a = abox[l];               // broadcast LDS read
                        float ix1 = fmaxf(qx1, a.x), iy1 = fmaxf(qy1, a.y);
                        float ix2 = fminf(qx2, a.z), iy2 = fminf(qy2, a.w);
                        float inter = fmaxf(ix2 - ix1, 0.0f) * fmaxf(iy2 - iy1, 0.0f);
                        float iou = inter / (aq + aarea[l] - inter);
                        if (iou > NMS_THR) dead = true;
                    }
                    // phase B: in-wave sequential resolve
                    uint64_t alive = __ballot(valid && !dead);
                    while (alive != 0ull && na < TOPN) {
                        int j = __ffsll((unsigned long long)alive) - 1;
                        uint64_t kj = __shfl((unsigned long long)myk, j, 64);
                        uint32_t oj = 0xFFFFFFFFu - (uint32_t)kj;
                        int pj = (int)(oj / NLBL);
                        int cj = (int)(oj - (uint32_t)pj * NLBL) + 1;
                        float4 dbj = dbox[pj];            // broadcast
                        float loj = (float)cj * ofb;      // bit-exact same exprs
                        float ax1 = dbj.x + loj, ay1 = dbj.y + loj;
                        float ax2 = dbj.z + loj, ay2 = dbj.w + loj;
                        float aa = (ax2 - ax1) * (ay2 - ay1);
                        if (lane == 0) {
                            abox[na]  = make_float4(ax1, ay1, ax2, ay2);
                            aarea[na] = aa;
                            float* o = out + ((size_t)b * TOPN + na) * 6;
                            o[0] = fminf(fmaxf(dbj.x, 0.0f), 1.0f);
                            o[1] = fminf(fmaxf(dbj.y, 0.0f), 1.0f);
                            o[2] = fminf(fmaxf(dbj.z, 0.0f), 1.0f);
                            o[3] = fminf(fmaxf(dbj.w, 0.0f), 1.0f);
                            o[4] = __uint_as_float((uint32_t)(kj >> 32));
                            o[5] = (float)cj;
                        }
                        na++;
                        bool mine = ((alive >> lane) & 1ull) != 0ull;
                        bool drop = (lane == j);          // force-remove accepted
                        if (mine && !drop) {
                            float ix1 = fmaxf(qx1, ax1), iy1 = fmaxf(qy1, ay1);
                            float ix2 = fminf(qx2, ax2), iy2 = fminf(qy2, ay2);
                            float inter = fmaxf(ix2 - ix1, 0.0f) * fmaxf(iy2 - iy1, 0.0f);
                            float iou = inter / (aq + aa - inter);
                            if (iou > NMS_THR) drop = true;
                        }
                        alive = __ballot(mine && !drop);
                    }
                }
                if (lane == 0) naS = na;
            } else {
                // ======== waves 1-15: decode 3000 priors -> LDS dbox ========
                if (!decoded) {
                    int base0 = (wave - 1) * 200;
                    float lmax = -FLT_MAX;
                    for (int p = base0 + lane; p < base0 + 200; p += 64) {
                        float4 d4 = ((const float4*)deltas)[(size_t)b * PRIORS + p];
                        float4 pr = ((const float4*)priors)[p];
                        float cx = d4.x * 0.1f * pr.z + pr.x;
                        float cy = d4.y * 0.1f * pr.w + pr.y;
                        float w  = expf(d4.z * 0.2f) * pr.z;
                        float h  = expf(d4.w * 0.2f) * pr.w;
                        float x1 = cx - 0.5f * w, y1 = cy - 0.5f * h;
                        float x2 = cx + 0.5f * w, y2 = cy + 0.5f * h;
                        dbox[p] = make_float4(x1, y1, x2, y2);
                        lmax = fmaxf(lmax, fmaxf(fmaxf(x1, y1), fmaxf(x2, y2)));
                    }
                    for (int d = 32; d > 0; d >>= 1)
                        lmax = fmaxf(lmax, __shfl_xor(lmax, d, 64));
                    if (lane == 0) wredF[wave] = lmax;
                }
                __syncthreads();   // pairs with wave 0's post-sort barrier
            }
            decoded = true;
            curHi = lo;
        } else {
            // ------- overfull stratum fallback (never with this data) -------
            if (!decoded) {
                float lmax = -FLT_MAX;
                for (int p = tid; p < PRIORS; p += NMS_T) {
                    float4 d4 = ((const float4*)deltas)[(size_t)b * PRIORS + p];
                    float4 pr = ((const float4*)priors)[p];
                    float cx = d4.x * 0.1f * pr.z + pr.x;
                    float cy = d4.y * 0.1f * pr.w + pr.y;
                    float w  = expf(d4.z * 0.2f) * pr.z;
                    float h  = expf(d4.w * 0.2f) * pr.w;
                    float x1 = cx - 0.5f * w, y1 = cy - 0.5f * h;
                    float x2 = cx + 0.5f * w, y2 = cy + 0.5f * h;
                    dbox[p] = make_float4(x1, y1, x2, y2);
                    lmax = fmaxf(lmax, fmaxf(fmaxf(x1, y1), fmaxf(x2, y2)));
                }
                for (int d = 32; d > 0; d >>= 1)
                    lmax = fmaxf(lmax, __shfl_xor(lmax, d, 64));
                if (lane == 0) wredF[wave] = lmax;
                __syncthreads();
                decoded = true;
            }
            float ofb;
            {
                float v = (lane < NMS_T / 64) ? wredF[lane] : -FLT_MAX;
                for (int d = 32; d > 0; d >>= 1) v = fmaxf(v, __shfl_xor(v, d, 64));
                ofb = v + 1.0f;
            }
            int s = curHi - 1;
            uint64_t lastK = ~0ull;
            for (;;) {
                __syncthreads();
                if (naS >= TOPN) break;
                uint64_t bk = 0ull;
                for (int j = tid; j < SLOTS; j += NMS_T) {
                    uint64_t k = slots[j];
                    if (k && key_stratum(k) == s && k < lastK && k > bk) bk = k;
                }
                for (int j = tid; j < n_ovf; j += NMS_T) {
                    uint64_t k = ovfp[j];
                    if (k && key_stratum(k) == s && k < lastK && k > bk) bk = k;
                }
                for (int d = 32; d > 0; d >>= 1) {
                    uint64_t o = __shfl_xor((unsigned long long)bk, d, 64);
                    bk = (o > bk) ? o : bk;
                }
                if (lane == 0) rk[wave] = bk;
                __syncthreads();
                if (tid == 0) {
                    uint64_t fk = rk[0];
                    for (int w = 1; w < NMS_T / 64; ++w) fk = (rk[w] > fk) ? rk[w] : fk;
                    fkS = fk;
                }
                __syncthreads();
                uint64_t fk = fkS;
                if (fk == 0ull) break;
                if (wave == 0) {
                    int nal = naS;
                    nal = scan_step_w0(fk, b, dbox, ofb, abox, aarea, nal, out, lane);
                    if (lane == 0) naS = nal;
                }
                lastK = fk;
            }
            curHi = s;
        }
    }
    // ---- zero-fill rows naS..99 (harness poisons d_out) ----
    __syncthreads();
    int naF = naS;
    for (int idx = tid; idx < (TOPN - naF) * 6; idx += NMS_T)
        out[(size_t)b * TOPN * 6 + (size_t)naF * 6 + idx] = 0.0f;
}

// ---------------------------------------------------------------------------
extern "C" void kernel_launch(void* const* d_in, const int* in_sizes, int n_in,
                              void* d_out, int out_size, void* d_ws, size_t ws_size,
                              hipStream_t stream)
{
    const float* deltas = (const float*)d_in[0];
    const float* obj    = (const float*)d_in[1];
    const float* priors = (const float*)d_in[2];
    float* out = (float*)d_out;

    char* ws = (char*)d_ws;
    int* cnt = (int*)ws;                                    // B ints (overflow)
    uint64_t* seg = (uint64_t*)(ws + 256);                  // B*SLOTS keys (6.2 MB)
    uint64_t* ovf = seg + (size_t)BATCH * SLOTS;            // B*OVF_CAP keys (128 KB)

    hipMemsetAsync(cnt, 0, BATCH * sizeof(int), stream);
    dim3 fg(FBLK, BATCH, 1);
    score_filter_kernel<<<fg, 256, 0, stream>>>(obj, cnt, seg, ovf);
    nms_kernel<<<BATCH, NMS_T, 0, stream>>>(deltas, priors, cnt, seg, ovf, out);
}